// Round 1
// baseline (140.817 us; speedup 1.0000x reference)
//
#include <hip/hip_runtime.h>
#include <math.h>

#define BB 64
#define SS 2048
#define DD 512
#define NU 512
#define WIN 128

__device__ __forceinline__ float wave_reduce_sum(float v) {
    #pragma unroll
    for (int off = 32; off > 0; off >>= 1)
        v += __shfl_down(v, off, 64);
    return v;
}

__device__ __forceinline__ float wave_reduce_max(float v) {
    #pragma unroll
    for (int off = 32; off > 0; off >>= 1)
        v = fmaxf(v, __shfl_down(v, off, 64));
    return v;
}

// Kernel 1: score[b,s] = dot(query[b], keys[b,s])  -- the 256 MiB read
__global__ __launch_bounds__(256) void score_kernel(const float* __restrict__ query,
                                                    const float* __restrict__ keys,
                                                    float* __restrict__ score) {
    const int b     = blockIdx.x >> 5;   // 32 chunks of 64 rows per batch
    const int chunk = blockIdx.x & 31;
    const int wave  = threadIdx.x >> 6;
    const int lane  = threadIdx.x & 63;

    // 8 query floats per lane, held in registers for all 16 rows
    const float4* qv = (const float4*)(query + b * DD + lane * 8);
    const float4 q0 = qv[0], q1 = qv[1];

    const float* krow = keys + (size_t)b * SS * DD;
    const int s0 = chunk * 64 + wave * 16;

    #pragma unroll 4
    for (int i = 0; i < 16; ++i) {
        const int s = s0 + i;
        const float4* kv = (const float4*)(krow + (size_t)s * DD + lane * 8);
        const float4 k0 = kv[0], k1 = kv[1];
        float p = q0.x*k0.x + q0.y*k0.y + q0.z*k0.z + q0.w*k0.w
                + q1.x*k1.x + q1.y*k1.y + q1.z*k1.z + q1.w*k1.w;
        p = wave_reduce_sum(p);
        if (lane == 0) score[b * SS + s] = p;
    }
}

// Kernel 2: predictive alignment p = L * sigmoid(tanh(q@Wq^T)@wp^T); store {g, start, end}
__global__ __launch_bounds__(256) void p_kernel(const float* __restrict__ query,
                                                const int* __restrict__ key_lengths,
                                                const float* __restrict__ Wq,
                                                const float* __restrict__ wp,
                                                float* __restrict__ ws) {
    const int b = blockIdx.x;
    const int wave = threadIdx.x >> 6;
    const int lane = threadIdx.x & 63;
    __shared__ float act[NU];
    __shared__ float wsum[4];

    const float4* qv = (const float4*)(query + b * DD + lane * 8);
    const float4 q0 = qv[0], q1 = qv[1];

    for (int u = wave; u < NU; u += 4) {
        const float4* wv = (const float4*)(Wq + (size_t)u * DD + lane * 8);
        const float4 w0 = wv[0], w1 = wv[1];
        float p = q0.x*w0.x + q0.y*w0.y + q0.z*w0.z + q0.w*w0.w
                + q1.x*w1.x + q1.y*w1.y + q1.z*w1.z + q1.w*w1.w;
        p = wave_reduce_sum(p);
        if (lane == 0) act[u] = tanhf(p);
    }
    __syncthreads();

    const int t = threadIdx.x;
    float sv = act[t] * wp[t] + act[t + 256] * wp[t + 256];
    sv = wave_reduce_sum(sv);
    if (lane == 0) wsum[wave] = sv;
    __syncthreads();

    if (t == 0) {
        const float s = wsum[0] + wsum[1] + wsum[2] + wsum[3];
        const float sig = 1.0f / (1.0f + expf(-s));
        const float L = (float)key_lengths[b];
        const float p = L * sig;
        const int start = (int)(p - (float)WIN);   // trunc toward zero == jnp.trunc+int32
        const int end   = (int)(p + (float)WIN);
        const float diff = L - p;
        const float g = expf(-(diff * diff) / (float)WIN);
        ws[b] = g;
        ((int*)ws)[BB + b]     = start;
        ((int*)ws)[2 * BB + b] = end;
    }
}

// Kernel 3: softmax over the score row + masked window weighted key sum.
// grid (B, 8): each single-wave block owns 64 d-columns of one batch.
__global__ __launch_bounds__(64) void ctx_kernel(const float* __restrict__ keys,
                                                 const float* __restrict__ score,
                                                 const float* __restrict__ ws,
                                                 float* __restrict__ ctx) {
    const int b = blockIdx.x;
    const int dchunk = blockIdx.y;
    const int lane = threadIdx.x;
    __shared__ float w_lds[512];

    const float* srow = score + b * SS;

    // softmax stats over S=2048: each lane loads 32 scores (coalesced float4)
    float4 svals[8];
    float m = -INFINITY;
    #pragma unroll
    for (int j = 0; j < 8; ++j) {
        svals[j] = ((const float4*)srow)[j * 64 + lane];
        m = fmaxf(m, fmaxf(fmaxf(svals[j].x, svals[j].y), fmaxf(svals[j].z, svals[j].w)));
    }
    m = wave_reduce_max(m);
    const float mx = __shfl(m, 0, 64);

    float sum = 0.f;
    #pragma unroll
    for (int j = 0; j < 8; ++j) {
        sum += expf(svals[j].x - mx) + expf(svals[j].y - mx)
             + expf(svals[j].z - mx) + expf(svals[j].w - mx);
    }
    sum = wave_reduce_sum(sum);
    const float inv = 1.0f / __shfl(sum, 0, 64);

    const float g = ws[b];
    const int start = ((const int*)ws)[BB + b];
    const int end   = ((const int*)ws)[2 * BB + b];
    const int s_lo = max(start, 0);
    const int s_hi = min(end, SS);
    const int width = s_hi - s_lo;   // <= 257

    for (int i = lane; i < width; i += 64)
        w_lds[i] = expf(srow[s_lo + i] - mx) * inv * g;
    __syncthreads();

    const int d = dchunk * 64 + lane;
    const float* kb = keys + (size_t)b * SS * DD + (size_t)s_lo * DD + d;
    float acc = 0.f;
    #pragma unroll 4
    for (int i = 0; i < width; ++i)
        acc += w_lds[i] * kb[(size_t)i * DD];

    ctx[b * DD + d] = acc;
}

extern "C" void kernel_launch(void* const* d_in, const int* in_sizes, int n_in,
                              void* d_out, int out_size, void* d_ws, size_t ws_size,
                              hipStream_t stream) {
    const float* query       = (const float*)d_in[0];
    const float* keys        = (const float*)d_in[1];
    const int*   key_lengths = (const int*)d_in[2];
    const float* Wq          = (const float*)d_in[3];
    const float* wp          = (const float*)d_in[4];

    float* ctx   = (float*)d_out;             // [64, 512]
    float* score = (float*)d_out + BB * DD;   // [64, 2048]
    float* ws    = (float*)d_ws;              // {g[64], start[64], end[64]}

    hipLaunchKernelGGL(score_kernel, dim3(BB * 32), dim3(256), 0, stream, query, keys, score);
    hipLaunchKernelGGL(p_kernel,     dim3(BB),      dim3(256), 0, stream, query, key_lengths, Wq, wp, ws);
    hipLaunchKernelGGL(ctx_kernel,   dim3(BB, 8),   dim3(64),  0, stream, keys, score, ws, ctx);
}

// Round 4
// 125.338 us; speedup vs baseline: 1.1235x; 1.1235x over previous
//
#include <hip/hip_runtime.h>
#include <math.h>

#define BB 64
#define SS 2048
#define DD 512
#define NU 512
#define WIN 128

__device__ __forceinline__ float wave_reduce_sum(float v) {
    #pragma unroll
    for (int off = 32; off > 0; off >>= 1)
        v += __shfl_down(v, off, 64);
    return v;
}

__device__ __forceinline__ float wave_reduce_max(float v) {
    #pragma unroll
    for (int off = 32; off > 0; off >>= 1)
        v = fmaxf(v, __shfl_down(v, off, 64));
    return v;
}

// Fused kernel 1: blocks [0, 2048) compute score; blocks [2048, 2112) compute
// the predictive-alignment params {g, start, end} (independent of score).
__global__ __launch_bounds__(256) void score_p_kernel(const float* __restrict__ query,
                                                      const float* __restrict__ keys,
                                                      const int* __restrict__ key_lengths,
                                                      const float* __restrict__ Wq,
                                                      const float* __restrict__ wp,
                                                      float* __restrict__ score,
                                                      float* __restrict__ ws) {
    const int wave = threadIdx.x >> 6;
    const int lane = threadIdx.x & 63;
    __shared__ float act[NU];
    __shared__ float wsum[4];

    if (blockIdx.x < BB * 32) {
        // ---- score path: 32 blocks per batch, 64 rows per block, 16 per wave
        const int b     = blockIdx.x >> 5;
        const int chunk = blockIdx.x & 31;

        const float4* qv = (const float4*)(query + b * DD);
        const float4 q0 = qv[lane], q1 = qv[lane + 64];   // contiguous 1KiB per instr

        const float* kbase = keys + (size_t)b * SS * DD;
        const int s0 = chunk * 64 + wave * 16;

        #pragma unroll 4
        for (int i = 0; i < 16; ++i) {
            const int s = s0 + i;
            const float4* kv = (const float4*)(kbase + (size_t)s * DD);
            const float4 k0 = kv[lane], k1 = kv[lane + 64];
            float p = q0.x*k0.x + q0.y*k0.y + q0.z*k0.z + q0.w*k0.w
                    + q1.x*k1.x + q1.y*k1.y + q1.z*k1.z + q1.w*k1.w;
            p = wave_reduce_sum(p);
            if (lane == 0) score[b * SS + s] = p;
        }
    } else {
        // ---- p path: one block per batch
        const int b = blockIdx.x - BB * 32;

        const float4* qv = (const float4*)(query + b * DD);
        const float4 q0 = qv[lane], q1 = qv[lane + 64];

        for (int u = wave; u < NU; u += 4) {
            const float4* wv = (const float4*)(Wq + (size_t)u * DD);
            const float4 w0 = wv[lane], w1 = wv[lane + 64];
            float p = q0.x*w0.x + q0.y*w0.y + q0.z*w0.z + q0.w*w0.w
                    + q1.x*w1.x + q1.y*w1.y + q1.z*w1.z + q1.w*w1.w;
            p = wave_reduce_sum(p);
            if (lane == 0) act[u] = tanhf(p);
        }
        __syncthreads();

        const int t = threadIdx.x;
        float sv = act[t] * wp[t] + act[t + 256] * wp[t + 256];
        sv = wave_reduce_sum(sv);
        if (lane == 0) wsum[wave] = sv;
        __syncthreads();

        if (t == 0) {
            const float s = wsum[0] + wsum[1] + wsum[2] + wsum[3];
            const float sig = 1.0f / (1.0f + expf(-s));
            const float L = (float)key_lengths[b];
            const float p = L * sig;
            const int start = (int)(p - (float)WIN);   // trunc toward zero
            const int end   = (int)(p + (float)WIN);
            const float diff = L - p;
            const float g = expf(-(diff * diff) / (float)WIN);
            ws[b] = g;
            ((int*)ws)[BB + b]     = start;
            ((int*)ws)[2 * BB + b] = end;
        }
    }
}

// Kernel 2: softmax stats + windowed weighted key sum.
// grid (B, 8) x 256 threads: block owns 64 d-columns; 4 waves split window rows.
__global__ __launch_bounds__(256) void ctx_kernel(const float* __restrict__ keys,
                                                  const float* __restrict__ score,
                                                  const float* __restrict__ ws,
                                                  float* __restrict__ ctx) {
    const int b      = blockIdx.x;
    const int dchunk = blockIdx.y;
    const int t      = threadIdx.x;
    const int wave   = t >> 6;
    const int lane   = t & 63;

    __shared__ float w_lds[2 * WIN + 4];
    __shared__ float redm[4], reds[4];
    __shared__ float part[4][64];

    const float* srow = score + b * SS;

    // softmax stats over S=2048: each thread loads 8 scores (2 x float4)
    const float4 v0 = ((const float4*)srow)[t];
    const float4 v1 = ((const float4*)srow)[t + 256];
    float m = fmaxf(fmaxf(fmaxf(v0.x, v0.y), fmaxf(v0.z, v0.w)),
                    fmaxf(fmaxf(v1.x, v1.y), fmaxf(v1.z, v1.w)));
    m = wave_reduce_max(m);
    if (lane == 0) redm[wave] = m;
    __syncthreads();
    const float mx = fmaxf(fmaxf(redm[0], redm[1]), fmaxf(redm[2], redm[3]));

    float sum = expf(v0.x - mx) + expf(v0.y - mx) + expf(v0.z - mx) + expf(v0.w - mx)
              + expf(v1.x - mx) + expf(v1.y - mx) + expf(v1.z - mx) + expf(v1.w - mx);
    sum = wave_reduce_sum(sum);
    if (lane == 0) reds[wave] = sum;
    __syncthreads();
    const float inv = 1.0f / (reds[0] + reds[1] + reds[2] + reds[3]);

    const float g = ws[b];
    const int start = ((const int*)ws)[BB + b];
    const int end   = ((const int*)ws)[2 * BB + b];
    const int s_lo = max(start, 0);
    const int s_hi = min(end, SS);
    const int width = s_hi - s_lo;   // <= 257 (can be <= 0)

    for (int i = t; i < width; i += 256)
        w_lds[i] = expf(srow[s_lo + i] - mx) * inv * g;
    __syncthreads();

    // accumulate: lane owns column d; waves stride the window rows
    const int d = dchunk * 64 + lane;
    const float* kb = keys + (size_t)b * SS * DD + (size_t)s_lo * DD + d;
    float acc = 0.f;
    for (int i = wave; i < width; i += 4)
        acc += w_lds[i] * kb[(size_t)i * DD];

    if (wave != 0) part[wave][lane] = acc;
    __syncthreads();
    if (wave == 0)
        ctx[b * DD + d] = acc + part[1][lane] + part[2][lane] + part[3][lane];
}

extern "C" void kernel_launch(void* const* d_in, const int* in_sizes, int n_in,
                              void* d_out, int out_size, void* d_ws, size_t ws_size,
                              hipStream_t stream) {
    const float* query       = (const float*)d_in[0];
    const float* keys        = (const float*)d_in[1];
    const int*   key_lengths = (const int*)d_in[2];
    const float* Wq          = (const float*)d_in[3];
    const float* wp          = (const float*)d_in[4];

    float* ctx   = (float*)d_out;             // [64, 512]
    float* score = (float*)d_out + BB * DD;   // [64, 2048]
    float* ws    = (float*)d_ws;              // {g[64], start[64], end[64]}

    hipLaunchKernelGGL(score_p_kernel, dim3(BB * 32 + BB), dim3(256), 0, stream,
                       query, keys, key_lengths, Wq, wp, score, ws);
    hipLaunchKernelGGL(ctx_kernel, dim3(BB, 8), dim3(256), 0, stream,
                       keys, score, ws, ctx);
}